// Round 4
// baseline (21785.529 us; speedup 1.0000x reference)
//
#include <hip/hip_runtime.h>
#include <hip/hip_bf16.h>
#include <math.h>

// Multilayer GRU: B=32, S=512, H=1024, L=3, O=1024.
// v4: layer-pipelined persistent kernel (192 blocks = 3 layers x 64).
// All cross-block data moves via inline-asm sc0/sc1 burst loads/stores:
// 16 global_load_dwordx4 back-to-back + ONE s_waitcnt (no per-load
// serialization, no VGPR blowup). Per-wave dependency gating: h-side waves
// gate on own-layer WAR flags, x-side waves on producer flags.

#define BB 32
#define SS 512
#define HH 1024
#define LL 3
#define OO 1024
#define SH (SS*HH)

typedef __attribute__((ext_vector_type(8))) short short8;
typedef __attribute__((ext_vector_type(4))) float float4v;
typedef unsigned long long u64;
typedef unsigned int u32;
typedef unsigned short u16;

__device__ __forceinline__ u16 f2bf(float f) {
  union { float f; u32 u; } v; v.f = f;
  return (u16)((v.u + 0x7FFFu + ((v.u >> 16) & 1u)) >> 16);
}

__global__ void convert_bf16(const float* __restrict__ src,
                             u16* __restrict__ dst, int n) {
  int stride = gridDim.x * blockDim.x;
  for (int i = blockIdx.x * blockDim.x + threadIdx.x; i < n; i += stride)
    dst[i] = f2bf(src[i]);
}

// hb[l][b][c] = bf16(h0[b][l][c])
__global__ void init_h(const float* __restrict__ h0, u16* __restrict__ hb) {
  int i = blockIdx.x * 256 + threadIdx.x;           // 98304 total
  int l = i >> 15, r = i & 32767, b = r >> 10, c = r & 1023;
  hb[i] = f2bf(h0[b * 3072 + l * 1024 + c]);
}

// Pack W[nmat][1024][1024] into MFMA B-fragment stream:
// dst[((row>>4)*32+(k>>5))*512 + lane*8 + (k&7)], lane = ((k>>3)&3)*16+(row&15)
__global__ void pack_w(const float* __restrict__ src, u16* __restrict__ dst,
                       int nmat) {
  int stride = gridDim.x * blockDim.x;
  int total = nmat * 1048576;
  for (int i = blockIdx.x * blockDim.x + threadIdx.x; i < total; i += stride) {
    int m = i >> 20, e = i & 1048575;
    int row = e >> 10, k = e & 1023;
    int lane = ((k >> 3) & 3) * 16 + (row & 15);
    int di = ((row >> 4) * 32 + (k >> 5)) * 512 + lane * 8 + (k & 7);
    dst[m * 1048576 + di] = f2bf(src[i]);
  }
}

// ---- coherent access primitives (cache-bypassing, burst-friendly) --------
__device__ __forceinline__ short8 ld_coh16(const u16* p) {
  short8 v;
  asm volatile("global_load_dwordx4 %0, %1, off sc0 sc1"
               : "=v"(v) : "v"(p) : "memory");
  return v;
}
__device__ __forceinline__ void wait_vm0() {
  asm volatile("s_waitcnt vmcnt(0)" ::: "memory");
  __builtin_amdgcn_sched_barrier(0);
}
__device__ __forceinline__ void coh_store_u16(u16* p, u16 v) {
  u32 vv = v;
  asm volatile("global_store_short %0, %1, off sc0 sc1"
               :: "v"(p), "v"(vv) : "memory");
}
__device__ __forceinline__ void coh_store_u32(int* p, int v) {
  asm volatile("global_store_dword %0, %1, off sc0 sc1"
               :: "v"(p), "v"(v) : "memory");
}
// poll 128 flags (2 per lane) until all >= tgt
__device__ __forceinline__ void poll128(const int* base, int lane, int tgt) {
  int f0, f1;
  do {
    asm volatile("global_load_dword %0, %2, off sc0 sc1\n\t"
                 "global_load_dword %1, %3, off sc0 sc1\n\t"
                 "s_waitcnt vmcnt(0)"
                 : "=v"(f0), "=v"(f1)
                 : "v"(base + lane), "v"(base + 64 + lane)
                 : "memory");
  } while (__any((f0 < tgt) | (f1 < tgt)));
}

#define MFMA16(a, b, c) __builtin_amdgcn_mfma_f32_16x16x32_bf16(a, b, c, 0, 0, 0)

__launch_bounds__(256, 1)
__global__ void gru_pipe(
    u16* __restrict__ buf0, u16* __restrict__ buf1,
    const u16* __restrict__ Pzh, const u16* __restrict__ Pzx,
    const u16* __restrict__ Prh, const u16* __restrict__ Prx,
    const u16* __restrict__ Pgh, const u16* __restrict__ Pgx,
    const float* __restrict__ bz, const float* __restrict__ br,
    const float* __restrict__ bg, const float* __restrict__ h0,
    u16* __restrict__ hb, u16* __restrict__ rh,
    float* __restrict__ hid, int* __restrict__ flagsD,
    int* __restrict__ flagsP) {
  const int grp = blockIdx.x >> 6;        // layer 0..2
  const int blk = blockIdx.x & 63;        // 16-col tile
  const int tid = threadIdx.x;
  const int lane = tid & 63;
  const int wave = tid >> 6;
  const int mt = wave & 1;                // M-tile: rows 0-15 / 16-31
  const int kh = wave >> 1;               // phase1 side: 0=h, 1=x
  const int fcol = lane & 15, kg = lane >> 4;
  const int arow = mt * 16 + fcol;
  const int crow0 = mt * 16 + kg * 4;
  const int colZ = blk * 16 + fcol;

  const u16* xin = (grp & 1) ? buf1 : buf0;
  u16* yout      = (grp & 1) ? buf0 : buf1;
  const size_t lw = (size_t)grp * 1048576;
  const u16* wZ  = (kh ? Pzx : Pzh) + lw + blk * 16384 + lane * 8;
  const u16* wR  = (kh ? Prx : Prh) + lw + blk * 16384 + lane * 8;
  const u16* wGx = Pgx + lw + blk * 16384 + lane * 8;
  const u16* wGh = Pgh + lw + blk * 16384 + lane * 8;
  u16* hbl = hb + grp * (BB * HH);
  u16* rhl = rh + grp * (BB * HH);
  int* selfD = flagsD + (grp + 1) * 128;
  int* prodD = flagsD + grp * 128;
  int* selfP = flagsP + grp * 128;

  __shared__ float redz[4][2][64], redr[4][2][64], redg[4][2][64];

  float hreg[4] = {0, 0, 0, 0}, zreg[4] = {0, 0, 0, 0};
  float bzv = 0, brv = 0, bgv = 0;
  if (kh == 0) {
#pragma unroll
    for (int q = 0; q < 4; ++q)
      hreg[q] = h0[(crow0 + q) * (LL * HH) + grp * HH + colZ];
    bzv = bz[grp * HH + colZ];
    brv = br[grp * HH + colZ];
    bgv = bg[grp * HH + colZ];
  }

  const u16* Ah = hbl + arow * HH;
  const u16* Ax = xin + (size_t)arow * SH;
  const u16* Ar = rhl + arow * HH + kh * 512;   // phase2 K-half base

  for (int t = 0; t < SS; ++t) {
    // ---- phase-1 gate (per-wave): kh0 needs own-layer WAR; kh1 needs x[t]
    if (kh == 0) poll128(selfD, lane, t);
    else         poll128(prodD, lane, t + 1);

    const u16* A1 = kh ? (Ax + (size_t)t * HH) : Ah;
    float4v az0 = {0,0,0,0}, az1 = {0,0,0,0};
    float4v ar0 = {0,0,0,0}, ar1 = {0,0,0,0};
    float4v ag0 = {0,0,0,0}, ag1 = {0,0,0,0};
    short8 cf[16];

    // chunk 0: ks 0..15 (burst loads, single wait)
#pragma unroll
    for (int k = 0; k < 16; ++k) cf[k] = ld_coh16(A1 + k * 32 + kg * 8);
    wait_vm0();
#pragma unroll
    for (int k = 0; k < 16; ++k) {
      short8 vz = *(const short8*)(wZ + k * 512);
      short8 vr = *(const short8*)(wR + k * 512);
      if (k & 1) { az1 = MFMA16(cf[k], vz, az1); ar1 = MFMA16(cf[k], vr, ar1); }
      else       { az0 = MFMA16(cf[k], vz, az0); ar0 = MFMA16(cf[k], vr, ar0); }
      if (kh == 1) {
        short8 vg = *(const short8*)(wGx + k * 512);
        if (k & 1) ag1 = MFMA16(cf[k], vg, ag1);
        else       ag0 = MFMA16(cf[k], vg, ag0);
      }
    }
    // chunk 1: ks 16..31
#pragma unroll
    for (int k = 0; k < 16; ++k) cf[k] = ld_coh16(A1 + (16 + k) * 32 + kg * 8);
    wait_vm0();
#pragma unroll
    for (int k = 0; k < 16; ++k) {
      short8 vz = *(const short8*)(wZ + (16 + k) * 512);
      short8 vr = *(const short8*)(wR + (16 + k) * 512);
      if (k & 1) { az1 = MFMA16(cf[k], vz, az1); ar1 = MFMA16(cf[k], vr, ar1); }
      else       { az0 = MFMA16(cf[k], vz, az0); ar0 = MFMA16(cf[k], vr, ar0); }
      if (kh == 1) {
        short8 vg = *(const short8*)(wGx + (16 + k) * 512);
        if (k & 1) ag1 = MFMA16(cf[k], vg, ag1);
        else       ag0 = MFMA16(cf[k], vg, ag0);
      }
    }
    if (kh == 1) {
#pragma unroll
      for (int q = 0; q < 4; ++q) {
        redz[q][mt][lane] = az0[q] + az1[q];
        redr[q][mt][lane] = ar0[q] + ar1[q];
      }
    }
    __syncthreads();

    if (kh == 0) {
      // finalize z,r; publish r*h; per-wave flag
#pragma unroll
      for (int q = 0; q < 4; ++q) {
        float pz = az0[q] + az1[q] + redz[q][mt][lane] + bzv;
        float pr = ar0[q] + ar1[q] + redr[q][mt][lane] + brv;
        zreg[q] = 1.f / (1.f + expf(-pz));
        float rv = 1.f / (1.f + expf(-pr));
        coh_store_u16(rhl + (crow0 + q) * HH + colZ, f2bf(rv * hreg[q]));
      }
      asm volatile("s_waitcnt vmcnt(0)" ::: "memory");
      if (lane == 0) coh_store_u32(selfP + blk * 2 + mt, t + 1);
    }

    // ---- phase-2 gate: all r*h published
    poll128(selfP, lane, t + 1);

    // rh frags: 16 per wave (K split by kh)
#pragma unroll
    for (int k = 0; k < 16; ++k) cf[k] = ld_coh16(Ar + k * 32 + kg * 8);
    wait_vm0();
#pragma unroll
    for (int k = 0; k < 16; ++k) {
      short8 vg = *(const short8*)(wGh + (kh * 16 + k) * 512);
      if (k & 1) ag1 = MFMA16(cf[k], vg, ag1);
      else       ag0 = MFMA16(cf[k], vg, ag0);
    }
    if (kh == 1) {
#pragma unroll
      for (int q = 0; q < 4; ++q) redg[q][mt][lane] = ag0[q] + ag1[q];
    }
    __syncthreads();

    if (kh == 0) {
#pragma unroll
      for (int q = 0; q < 4; ++q) {
        float pg = ag0[q] + ag1[q] + redg[q][mt][lane] + bgv;
        float gv = tanhf(pg);
        float hn = zreg[q] * hreg[q] + (1.f - zreg[q]) * gv;
        hreg[q] = hn;
        u16 hv = f2bf(hn);
        const int row = crow0 + q;
        coh_store_u16(hbl + row * HH + colZ, hv);
        coh_store_u16(yout + (size_t)row * SH + (size_t)t * HH + colZ, hv);
        if (t == SS - 1) hid[row * (LL * HH) + grp * HH + colZ] = hn;
      }
      asm volatile("s_waitcnt vmcnt(0)" ::: "memory");
      if (lane == 0) coh_store_u32(selfD + blk * 2 + mt, t + 1);
    }
  }
}

// C[16384,1024] = A[16384,1024](bf16) @ W^T(bf16 rows) + bo
__launch_bounds__(64)
__global__ void out_gemm(const u16* __restrict__ A, const u16* __restrict__ W,
                         const float* __restrict__ bo, float* __restrict__ C) {
  const int lane = threadIdx.x;
  const int nt4 = blockIdx.x & 15;
  const int mt4 = blockIdx.x >> 4;
  const int r0 = mt4 * 64, n0 = nt4 * 64;
  const int fcol = lane & 15, kg = lane >> 4;
  float4v acc[4][4];
#pragma unroll
  for (int i = 0; i < 4; ++i)
#pragma unroll
    for (int j = 0; j < 4; ++j) acc[i][j] = (float4v){0, 0, 0, 0};

  for (int ks = 0; ks < 32; ++ks) {
    short8 a[4], b[4];
#pragma unroll
    for (int i = 0; i < 4; ++i)
      a[i] = *(const short8*)(A + (size_t)(r0 + i * 16 + fcol) * HH + ks * 32 + kg * 8);
#pragma unroll
    for (int j = 0; j < 4; ++j)
      b[j] = *(const short8*)(W + (size_t)(n0 + j * 16 + fcol) * HH + ks * 32 + kg * 8);
#pragma unroll
    for (int i = 0; i < 4; ++i)
#pragma unroll
      for (int j = 0; j < 4; ++j)
        acc[i][j] = MFMA16(a[i], b[j], acc[i][j]);
  }
#pragma unroll
  for (int i = 0; i < 4; ++i)
#pragma unroll
    for (int j = 0; j < 4; ++j)
#pragma unroll
      for (int q = 0; q < 4; ++q) {
        int R = r0 + i * 16 + kg * 4 + q;
        int col = n0 + j * 16 + fcol;
        C[(size_t)R * OO + col] = acc[i][j][q] + bo[col];
      }
}

extern "C" void kernel_launch(void* const* d_in, const int* in_sizes, int n_in,
                              void* d_out, int out_size, void* d_ws, size_t ws_size,
                              hipStream_t stream) {
  (void)in_sizes; (void)n_in; (void)out_size; (void)ws_size;

  const float* x   = (const float*)d_in[0];
  const float* h0  = (const float*)d_in[1];
  const float* Wzx = (const float*)d_in[2];
  const float* bz  = (const float*)d_in[3];
  const float* Wzh = (const float*)d_in[4];
  const float* Wrx = (const float*)d_in[5];
  const float* br  = (const float*)d_in[6];
  const float* Wrh = (const float*)d_in[7];
  const float* Wgx = (const float*)d_in[8];
  const float* bg  = (const float*)d_in[9];
  const float* Wgh = (const float*)d_in[10];
  const float* Wo  = (const float*)d_in[11];
  const float* bo  = (const float*)d_in[12];
  float* out = (float*)d_out;

  // ws layout (~103 MB)
  u16* Pzh = (u16*)d_ws;
  u16* Pzx = Pzh + 3145728;
  u16* Prh = Pzx + 3145728;
  u16* Prx = Prh + 3145728;
  u16* Pgh = Prx + 3145728;
  u16* Pgx = Pgh + 3145728;
  u16* Wob = Pgx + 3145728;            // 1M elems
  u16* buf0 = Wob + 1048576;           // 16.7M elems
  u16* buf1 = buf0 + 16777216;
  u16* hbw  = buf1 + 16777216;         // [3][B][H]
  u16* rhw  = hbw + 3 * BB * HH;       // [3][B][H]
  int* flagsD = (int*)(rhw + 3 * BB * HH);  // 4 groups x 128
  int* flagsP = flagsD + 512;               // 3 groups x 128

  hipMemsetAsync(flagsD, 0x7F, 128 * sizeof(int), stream);   // dummy producer
  hipMemsetAsync(flagsD + 128, 0, 384 * sizeof(int), stream);
  hipMemsetAsync(flagsP, 0, 384 * sizeof(int), stream);

  pack_w<<<3072, 256, 0, stream>>>(Wzh, Pzh, 3);
  pack_w<<<3072, 256, 0, stream>>>(Wzx, Pzx, 3);
  pack_w<<<3072, 256, 0, stream>>>(Wrh, Prh, 3);
  pack_w<<<3072, 256, 0, stream>>>(Wrx, Prx, 3);
  pack_w<<<3072, 256, 0, stream>>>(Wgh, Pgh, 3);
  pack_w<<<3072, 256, 0, stream>>>(Wgx, Pgx, 3);
  convert_bf16<<<256, 256, 0, stream>>>(Wo, Wob, 1048576);
  convert_bf16<<<2048, 256, 0, stream>>>(x, buf0, 16777216);
  init_h<<<384, 256, 0, stream>>>(h0, hbw);

  gru_pipe<<<192, 256, 0, stream>>>(
      buf0, buf1, Pzh, Pzx, Prh, Prx, Pgh, Pgx,
      bz, br, bg, h0, hbw, rhw, out + 16777216, flagsD, flagsP);

  out_gemm<<<4096, 64, 0, stream>>>(buf1, Wob, bo, out);
}

// Round 6
// 21769.525 us; speedup vs baseline: 1.0007x; 1.0007x over previous
//
#include <hip/hip_runtime.h>
#include <hip/hip_bf16.h>
#include <math.h>

// Multilayer GRU: B=32, S=512, H=1024, L=3, O=1024.
// v6: v4 structure (layer-pipelined persistent kernel, 192 blocks = 3x64,
// burst fragment loads with single vmcnt wait, per-wave dependency gating)
// with the empirically-pinned coherent-load bits:
//   loads  = sc1 only  (agent-coherent, L2-cacheable; what v3's
//            __hip_atomic_load(AGENT) emitted -- 1.27GB FETCH, correct)
//   stores = sc0 sc1   (write-through + invalidate = visibility mechanism)
// sc0-only loads hang (stale lines never invalidated, v5); sc0sc1 loads
// force read-through (10.6GB FETCH, v4 regression).

#define BB 32
#define SS 512
#define HH 1024
#define LL 3
#define OO 1024
#define SH (SS*HH)

typedef __attribute__((ext_vector_type(8))) short short8;
typedef __attribute__((ext_vector_type(4))) float float4v;
typedef unsigned long long u64;
typedef unsigned int u32;
typedef unsigned short u16;

__device__ __forceinline__ u16 f2bf(float f) {
  union { float f; u32 u; } v; v.f = f;
  return (u16)((v.u + 0x7FFFu + ((v.u >> 16) & 1u)) >> 16);
}

__global__ void convert_bf16(const float* __restrict__ src,
                             u16* __restrict__ dst, int n) {
  int stride = gridDim.x * blockDim.x;
  for (int i = blockIdx.x * blockDim.x + threadIdx.x; i < n; i += stride)
    dst[i] = f2bf(src[i]);
}

// hb[l][b][c] = bf16(h0[b][l][c])
__global__ void init_h(const float* __restrict__ h0, u16* __restrict__ hb) {
  int i = blockIdx.x * 256 + threadIdx.x;           // 98304 total
  int l = i >> 15, r = i & 32767, b = r >> 10, c = r & 1023;
  hb[i] = f2bf(h0[b * 3072 + l * 1024 + c]);
}

// Pack W[nmat][1024][1024] into MFMA B-fragment stream:
// dst[((row>>4)*32+(k>>5))*512 + lane*8 + (k&7)], lane = ((k>>3)&3)*16+(row&15)
__global__ void pack_w(const float* __restrict__ src, u16* __restrict__ dst,
                       int nmat) {
  int stride = gridDim.x * blockDim.x;
  int total = nmat * 1048576;
  for (int i = blockIdx.x * blockDim.x + threadIdx.x; i < total; i += stride) {
    int m = i >> 20, e = i & 1048575;
    int row = e >> 10, k = e & 1023;
    int lane = ((k >> 3) & 3) * 16 + (row & 15);
    int di = ((row >> 4) * 32 + (k >> 5)) * 512 + lane * 8 + (k & 7);
    dst[m * 1048576 + di] = f2bf(src[i]);
  }
}

// ---- access primitives ----------------------------------------------------
__device__ __forceinline__ short8 ld_frag(const u16* p) {
  short8 v;
  asm volatile("global_load_dwordx4 %0, %1, off sc1"
               : "=v"(v) : "v"(p) : "memory");
  return v;
}
__device__ __forceinline__ void wait_vm0() {
  asm volatile("s_waitcnt vmcnt(0)" ::: "memory");
  __builtin_amdgcn_sched_barrier(0);
}
__device__ __forceinline__ void coh_store_u16(u16* p, u16 v) {
  u32 vv = v;
  asm volatile("global_store_short %0, %1, off sc0 sc1"
               :: "v"(p), "v"(vv) : "memory");
}
__device__ __forceinline__ void coh_store_u32(int* p, int v) {
  asm volatile("global_store_dword %0, %1, off sc0 sc1"
               :: "v"(p), "v"(v) : "memory");
}
// poll 128 flags (2 per lane) until all >= tgt; sc1 (agent-coherent) loads
__device__ __forceinline__ void poll128(const int* base, int lane, int tgt) {
  int f0, f1;
  do {
    asm volatile("global_load_dword %0, %2, off sc1\n\t"
                 "global_load_dword %1, %3, off sc1\n\t"
                 "s_waitcnt vmcnt(0)"
                 : "=v"(f0), "=v"(f1)
                 : "v"(base + lane), "v"(base + 64 + lane)
                 : "memory");
  } while (__any((f0 < tgt) | (f1 < tgt)));
}

#define MFMA16(a, b, c) __builtin_amdgcn_mfma_f32_16x16x32_bf16(a, b, c, 0, 0, 0)

__launch_bounds__(256, 1)
__global__ void gru_pipe(
    u16* __restrict__ buf0, u16* __restrict__ buf1,
    const u16* __restrict__ Pzh, const u16* __restrict__ Pzx,
    const u16* __restrict__ Prh, const u16* __restrict__ Prx,
    const u16* __restrict__ Pgh, const u16* __restrict__ Pgx,
    const float* __restrict__ bz, const float* __restrict__ br,
    const float* __restrict__ bg, const float* __restrict__ h0,
    u16* __restrict__ hb, u16* __restrict__ rh,
    float* __restrict__ hid, int* __restrict__ flagsD,
    int* __restrict__ flagsP) {
  const int grp = blockIdx.x >> 6;        // layer 0..2
  const int blk = blockIdx.x & 63;        // 16-col tile
  const int tid = threadIdx.x;
  const int lane = tid & 63;
  const int wave = tid >> 6;
  const int mt = wave & 1;                // M-tile: rows 0-15 / 16-31
  const int kh = wave >> 1;               // phase1 side: 0=h, 1=x
  const int fcol = lane & 15, kg = lane >> 4;
  const int arow = mt * 16 + fcol;
  const int crow0 = mt * 16 + kg * 4;
  const int colZ = blk * 16 + fcol;

  const u16* xin = (grp & 1) ? buf1 : buf0;
  u16* yout      = (grp & 1) ? buf0 : buf1;
  const size_t lw = (size_t)grp * 1048576;
  const u16* wZ  = (kh ? Pzx : Pzh) + lw + blk * 16384 + lane * 8;
  const u16* wR  = (kh ? Prx : Prh) + lw + blk * 16384 + lane * 8;
  const u16* wGx = Pgx + lw + blk * 16384 + lane * 8;
  const u16* wGh = Pgh + lw + blk * 16384 + lane * 8;
  u16* hbl = hb + grp * (BB * HH);
  u16* rhl = rh + grp * (BB * HH);
  int* selfD = flagsD + (grp + 1) * 128;
  int* prodD = flagsD + grp * 128;
  int* selfP = flagsP + grp * 128;

  __shared__ float redz[4][2][64], redr[4][2][64], redg[4][2][64];

  float hreg[4] = {0, 0, 0, 0}, zreg[4] = {0, 0, 0, 0};
  float bzv = 0, brv = 0, bgv = 0;
  if (kh == 0) {
#pragma unroll
    for (int q = 0; q < 4; ++q)
      hreg[q] = h0[(crow0 + q) * (LL * HH) + grp * HH + colZ];
    bzv = bz[grp * HH + colZ];
    brv = br[grp * HH + colZ];
    bgv = bg[grp * HH + colZ];
  }

  const u16* Ah = hbl + arow * HH;
  const u16* Ax = xin + (size_t)arow * SH;
  const u16* Ar = rhl + arow * HH + kh * 512;   // phase2 K-half base

  for (int t = 0; t < SS; ++t) {
    // ---- phase-1 gate (per-wave): kh0 needs own-layer WAR; kh1 needs x[t]
    if (kh == 0) poll128(selfD, lane, t);
    else         poll128(prodD, lane, t + 1);

    const u16* A1 = kh ? (Ax + (size_t)t * HH) : Ah;
    float4v az0 = {0,0,0,0}, az1 = {0,0,0,0};
    float4v ar0 = {0,0,0,0}, ar1 = {0,0,0,0};
    float4v ag0 = {0,0,0,0}, ag1 = {0,0,0,0};
    short8 cf[16];

    // chunk 0: ks 0..15 (burst loads, single wait)
#pragma unroll
    for (int k = 0; k < 16; ++k) cf[k] = ld_frag(A1 + k * 32 + kg * 8);
    wait_vm0();
#pragma unroll
    for (int k = 0; k < 16; ++k) {
      short8 vz = *(const short8*)(wZ + k * 512);
      short8 vr = *(const short8*)(wR + k * 512);
      if (k & 1) { az1 = MFMA16(cf[k], vz, az1); ar1 = MFMA16(cf[k], vr, ar1); }
      else       { az0 = MFMA16(cf[k], vz, az0); ar0 = MFMA16(cf[k], vr, ar0); }
      if (kh == 1) {
        short8 vg = *(const short8*)(wGx + k * 512);
        if (k & 1) ag1 = MFMA16(cf[k], vg, ag1);
        else       ag0 = MFMA16(cf[k], vg, ag0);
      }
    }
    // chunk 1: ks 16..31
#pragma unroll
    for (int k = 0; k < 16; ++k) cf[k] = ld_frag(A1 + (16 + k) * 32 + kg * 8);
    wait_vm0();
#pragma unroll
    for (int k = 0; k < 16; ++k) {
      short8 vz = *(const short8*)(wZ + (16 + k) * 512);
      short8 vr = *(const short8*)(wR + (16 + k) * 512);
      if (k & 1) { az1 = MFMA16(cf[k], vz, az1); ar1 = MFMA16(cf[k], vr, ar1); }
      else       { az0 = MFMA16(cf[k], vz, az0); ar0 = MFMA16(cf[k], vr, ar0); }
      if (kh == 1) {
        short8 vg = *(const short8*)(wGx + (16 + k) * 512);
        if (k & 1) ag1 = MFMA16(cf[k], vg, ag1);
        else       ag0 = MFMA16(cf[k], vg, ag0);
      }
    }
    if (kh == 1) {
#pragma unroll
      for (int q = 0; q < 4; ++q) {
        redz[q][mt][lane] = az0[q] + az1[q];
        redr[q][mt][lane] = ar0[q] + ar1[q];
      }
    }
    __syncthreads();

    if (kh == 0) {
      // finalize z,r; publish r*h; per-wave flag
#pragma unroll
      for (int q = 0; q < 4; ++q) {
        float pz = az0[q] + az1[q] + redz[q][mt][lane] + bzv;
        float pr = ar0[q] + ar1[q] + redr[q][mt][lane] + brv;
        zreg[q] = 1.f / (1.f + expf(-pz));
        float rv = 1.f / (1.f + expf(-pr));
        coh_store_u16(rhl + (crow0 + q) * HH + colZ, f2bf(rv * hreg[q]));
      }
      asm volatile("s_waitcnt vmcnt(0)" ::: "memory");
      if (lane == 0) coh_store_u32(selfP + blk * 2 + mt, t + 1);
    }

    // ---- phase-2 gate: all r*h published
    poll128(selfP, lane, t + 1);

    // rh frags: 16 per wave (K split by kh)
#pragma unroll
    for (int k = 0; k < 16; ++k) cf[k] = ld_frag(Ar + k * 32 + kg * 8);
    wait_vm0();
#pragma unroll
    for (int k = 0; k < 16; ++k) {
      short8 vg = *(const short8*)(wGh + (kh * 16 + k) * 512);
      if (k & 1) ag1 = MFMA16(cf[k], vg, ag1);
      else       ag0 = MFMA16(cf[k], vg, ag0);
    }
    if (kh == 1) {
#pragma unroll
      for (int q = 0; q < 4; ++q) redg[q][mt][lane] = ag0[q] + ag1[q];
    }
    __syncthreads();

    if (kh == 0) {
#pragma unroll
      for (int q = 0; q < 4; ++q) {
        float pg = ag0[q] + ag1[q] + redg[q][mt][lane] + bgv;
        float gv = tanhf(pg);
        float hn = zreg[q] * hreg[q] + (1.f - zreg[q]) * gv;
        hreg[q] = hn;
        u16 hv = f2bf(hn);
        const int row = crow0 + q;
        coh_store_u16(hbl + row * HH + colZ, hv);
        coh_store_u16(yout + (size_t)row * SH + (size_t)t * HH + colZ, hv);
        if (t == SS - 1) hid[row * (LL * HH) + grp * HH + colZ] = hn;
      }
      asm volatile("s_waitcnt vmcnt(0)" ::: "memory");
      if (lane == 0) coh_store_u32(selfD + blk * 2 + mt, t + 1);
    }
  }
}

// C[16384,1024] = A[16384,1024](bf16) @ W^T(bf16 rows) + bo
__launch_bounds__(64)
__global__ void out_gemm(const u16* __restrict__ A, const u16* __restrict__ W,
                         const float* __restrict__ bo, float* __restrict__ C) {
  const int lane = threadIdx.x;
  const int nt4 = blockIdx.x & 15;
  const int mt4 = blockIdx.x >> 4;
  const int r0 = mt4 * 64, n0 = nt4 * 64;
  const int fcol = lane & 15, kg = lane >> 4;
  float4v acc[4][4];
#pragma unroll
  for (int i = 0; i < 4; ++i)
#pragma unroll
    for (int j = 0; j < 4; ++j) acc[i][j] = (float4v){0, 0, 0, 0};

  for (int ks = 0; ks < 32; ++ks) {
    short8 a[4], b[4];
#pragma unroll
    for (int i = 0; i < 4; ++i)
      a[i] = *(const short8*)(A + (size_t)(r0 + i * 16 + fcol) * HH + ks * 32 + kg * 8);
#pragma unroll
    for (int j = 0; j < 4; ++j)
      b[j] = *(const short8*)(W + (size_t)(n0 + j * 16 + fcol) * HH + ks * 32 + kg * 8);
#pragma unroll
    for (int i = 0; i < 4; ++i)
#pragma unroll
      for (int j = 0; j < 4; ++j)
        acc[i][j] = MFMA16(a[i], b[j], acc[i][j]);
  }
#pragma unroll
  for (int i = 0; i < 4; ++i)
#pragma unroll
    for (int j = 0; j < 4; ++j)
#pragma unroll
      for (int q = 0; q < 4; ++q) {
        int R = r0 + i * 16 + kg * 4 + q;
        int col = n0 + j * 16 + fcol;
        C[(size_t)R * OO + col] = acc[i][j][q] + bo[col];
      }
}

extern "C" void kernel_launch(void* const* d_in, const int* in_sizes, int n_in,
                              void* d_out, int out_size, void* d_ws, size_t ws_size,
                              hipStream_t stream) {
  (void)in_sizes; (void)n_in; (void)out_size; (void)ws_size;

  const float* x   = (const float*)d_in[0];
  const float* h0  = (const float*)d_in[1];
  const float* Wzx = (const float*)d_in[2];
  const float* bz  = (const float*)d_in[3];
  const float* Wzh = (const float*)d_in[4];
  const float* Wrx = (const float*)d_in[5];
  const float* br  = (const float*)d_in[6];
  const float* Wrh = (const float*)d_in[7];
  const float* Wgx = (const float*)d_in[8];
  const float* bg  = (const float*)d_in[9];
  const float* Wgh = (const float*)d_in[10];
  const float* Wo  = (const float*)d_in[11];
  const float* bo  = (const float*)d_in[12];
  float* out = (float*)d_out;

  // ws layout (~103 MB)
  u16* Pzh = (u16*)d_ws;
  u16* Pzx = Pzh + 3145728;
  u16* Prh = Pzx + 3145728;
  u16* Prx = Prh + 3145728;
  u16* Pgh = Prx + 3145728;
  u16* Pgx = Pgh + 3145728;
  u16* Wob = Pgx + 3145728;            // 1M elems
  u16* buf0 = Wob + 1048576;           // 16.7M elems
  u16* buf1 = buf0 + 16777216;
  u16* hbw  = buf1 + 16777216;         // [3][B][H]
  u16* rhw  = hbw + 3 * BB * HH;       // [3][B][H]
  int* flagsD = (int*)(rhw + 3 * BB * HH);  // 4 groups x 128
  int* flagsP = flagsD + 512;               // 3 groups x 128

  hipMemsetAsync(flagsD, 0x7F, 128 * sizeof(int), stream);   // dummy producer
  hipMemsetAsync(flagsD + 128, 0, 384 * sizeof(int), stream);
  hipMemsetAsync(flagsP, 0, 384 * sizeof(int), stream);

  pack_w<<<3072, 256, 0, stream>>>(Wzh, Pzh, 3);
  pack_w<<<3072, 256, 0, stream>>>(Wzx, Pzx, 3);
  pack_w<<<3072, 256, 0, stream>>>(Wrh, Prh, 3);
  pack_w<<<3072, 256, 0, stream>>>(Wrx, Prx, 3);
  pack_w<<<3072, 256, 0, stream>>>(Wgh, Pgh, 3);
  pack_w<<<3072, 256, 0, stream>>>(Wgx, Pgx, 3);
  convert_bf16<<<256, 256, 0, stream>>>(Wo, Wob, 1048576);
  convert_bf16<<<2048, 256, 0, stream>>>(x, buf0, 16777216);
  init_h<<<384, 256, 0, stream>>>(h0, hbw);

  gru_pipe<<<192, 256, 0, stream>>>(
      buf0, buf1, Pzh, Pzx, Prh, Prx, Pgh, Pgx,
      bz, br, bg, h0, hbw, rhw, out + 16777216, flagsD, flagsP);

  out_gemm<<<4096, 64, 0, stream>>>(buf1, Wob, bo, out);
}

// Round 7
// 14462.671 us; speedup vs baseline: 1.5063x; 1.5052x over previous
//
#include <hip/hip_runtime.h>
#include <hip/hip_bf16.h>
#include <math.h>

// Multilayer GRU: B=32, S=512, H=1024, L=3, O=1024.
// v7: layer-pipelined persistent kernel (192 blocks = 3 layers x 64) with
// v4's structure (per-wave dependency gating, g's x-side GEMM hidden under
// the rh barrier, chunked fragment loads, 2 syncthreads/step) and v3's
// proven coherent-load primitive: __hip_atomic_load(AGENT, relaxed) -- the
// only load flavor that is BOTH cross-XCD coherent AND L3-served (asm sc1
// loads are HBM-served: 10.6GB FETCH, 2x slower; sc0 loads are stale/hang).
// Stores remain sc0 sc1 write-through (visibility mechanism). Flag polls
// back off with s_sleep to cut the read storm.

#define BB 32
#define SS 512
#define HH 1024
#define LL 3
#define OO 1024
#define SH (SS*HH)

typedef __attribute__((ext_vector_type(8))) short short8;
typedef __attribute__((ext_vector_type(4))) float float4v;
typedef unsigned long long u64;
typedef unsigned int u32;
typedef unsigned short u16;

__device__ __forceinline__ u16 f2bf(float f) {
  union { float f; u32 u; } v; v.f = f;
  return (u16)((v.u + 0x7FFFu + ((v.u >> 16) & 1u)) >> 16);
}

__global__ void convert_bf16(const float* __restrict__ src,
                             u16* __restrict__ dst, int n) {
  int stride = gridDim.x * blockDim.x;
  for (int i = blockIdx.x * blockDim.x + threadIdx.x; i < n; i += stride)
    dst[i] = f2bf(src[i]);
}

// hb[l][b][c] = bf16(h0[b][l][c])
__global__ void init_h(const float* __restrict__ h0, u16* __restrict__ hb) {
  int i = blockIdx.x * 256 + threadIdx.x;           // 98304 total
  int l = i >> 15, r = i & 32767, b = r >> 10, c = r & 1023;
  hb[i] = f2bf(h0[b * 3072 + l * 1024 + c]);
}

// Pack W[nmat][1024][1024] into MFMA B-fragment stream:
// dst[((row>>4)*32+(k>>5))*512 + lane*8 + (k&7)], lane = ((k>>3)&3)*16+(row&15)
__global__ void pack_w(const float* __restrict__ src, u16* __restrict__ dst,
                       int nmat) {
  int stride = gridDim.x * blockDim.x;
  int total = nmat * 1048576;
  for (int i = blockIdx.x * blockDim.x + threadIdx.x; i < total; i += stride) {
    int m = i >> 20, e = i & 1048575;
    int row = e >> 10, k = e & 1023;
    int lane = ((k >> 3) & 3) * 16 + (row & 15);
    int di = ((row >> 4) * 32 + (k >> 5)) * 512 + lane * 8 + (k & 7);
    dst[m * 1048576 + di] = f2bf(src[i]);
  }
}

// ---- access primitives ----------------------------------------------------
// coherent L3-served 16B fragment load (2 x 8B agent-scope atomic loads)
__device__ __forceinline__ short8 coh16(const u16* p) {
  const u64* q = (const u64*)p;
  union { u64 q[2]; short8 v; } u;
  u.q[0] = __hip_atomic_load(q,     __ATOMIC_RELAXED, __HIP_MEMORY_SCOPE_AGENT);
  u.q[1] = __hip_atomic_load(q + 1, __ATOMIC_RELAXED, __HIP_MEMORY_SCOPE_AGENT);
  return u.v;
}
__device__ __forceinline__ void coh_store_u16(u16* p, u16 v) {
  u32 vv = v;
  asm volatile("global_store_short %0, %1, off sc0 sc1"
               :: "v"(p), "v"(vv) : "memory");
}
__device__ __forceinline__ void coh_store_u32(int* p, int v) {
  asm volatile("global_store_dword %0, %1, off sc0 sc1"
               :: "v"(p), "v"(v) : "memory");
}
// poll 128 flags (2 per lane) until all >= tgt; backoff between rounds
__device__ __forceinline__ void poll2(const int* base, int lane, int tgt) {
  const int* p0 = base + lane;
  const int* p1 = base + 64 + lane;
  int f0 = __hip_atomic_load(p0, __ATOMIC_RELAXED, __HIP_MEMORY_SCOPE_AGENT);
  int f1 = __hip_atomic_load(p1, __ATOMIC_RELAXED, __HIP_MEMORY_SCOPE_AGENT);
  while (__any((f0 < tgt) | (f1 < tgt))) {
    __builtin_amdgcn_s_sleep(1);
    f0 = __hip_atomic_load(p0, __ATOMIC_RELAXED, __HIP_MEMORY_SCOPE_AGENT);
    f1 = __hip_atomic_load(p1, __ATOMIC_RELAXED, __HIP_MEMORY_SCOPE_AGENT);
  }
}

#define MFMA16(a, b, c) __builtin_amdgcn_mfma_f32_16x16x32_bf16(a, b, c, 0, 0, 0)

__launch_bounds__(256, 1)
__global__ void gru_pipe(
    u16* __restrict__ buf0, u16* __restrict__ buf1,
    const u16* __restrict__ Pzh, const u16* __restrict__ Pzx,
    const u16* __restrict__ Prh, const u16* __restrict__ Prx,
    const u16* __restrict__ Pgh, const u16* __restrict__ Pgx,
    const float* __restrict__ bz, const float* __restrict__ br,
    const float* __restrict__ bg, const float* __restrict__ h0,
    u16* __restrict__ hb, u16* __restrict__ rh,
    float* __restrict__ hid, int* __restrict__ flagsD,
    int* __restrict__ flagsP) {
  const int grp = blockIdx.x >> 6;        // layer 0..2
  const int blk = blockIdx.x & 63;        // 16-col tile
  const int tid = threadIdx.x;
  const int lane = tid & 63;
  const int wave = tid >> 6;
  const int mt = wave & 1;                // M-tile: rows 0-15 / 16-31
  const int kh = wave >> 1;               // phase1 side: 0=h, 1=x
  const int fcol = lane & 15, kg = lane >> 4;
  const int arow = mt * 16 + fcol;
  const int crow0 = mt * 16 + kg * 4;
  const int colZ = blk * 16 + fcol;

  const u16* xin = (grp & 1) ? buf1 : buf0;
  u16* yout      = (grp & 1) ? buf0 : buf1;
  const size_t lw = (size_t)grp * 1048576;
  const u16* wZ  = (kh ? Pzx : Pzh) + lw + blk * 16384 + lane * 8;
  const u16* wR  = (kh ? Prx : Prh) + lw + blk * 16384 + lane * 8;
  const u16* wGx = Pgx + lw + blk * 16384 + lane * 8;
  const u16* wGh = Pgh + lw + blk * 16384 + lane * 8;
  u16* hbl = hb + grp * (BB * HH);
  u16* rhl = rh + grp * (BB * HH);
  int* selfD = flagsD + (grp + 1) * 128;
  int* prodD = flagsD + grp * 128;
  int* selfP = flagsP + grp * 128;

  __shared__ float redz[4][2][64], redr[4][2][64], redg[4][2][64];

  float hreg[4] = {0, 0, 0, 0}, zreg[4] = {0, 0, 0, 0};
  float bzv = 0, brv = 0, bgv = 0;
  if (kh == 0) {
#pragma unroll
    for (int q = 0; q < 4; ++q)
      hreg[q] = h0[(crow0 + q) * (LL * HH) + grp * HH + colZ];
    bzv = bz[grp * HH + colZ];
    brv = br[grp * HH + colZ];
    bgv = bg[grp * HH + colZ];
  }

  const u16* Ah = hbl + arow * HH;
  const u16* Ax = xin + (size_t)arow * SH;
  const u16* Ar = rhl + arow * HH + kh * 512;   // phase2 K-half base
  // layer0's x input is never written during this kernel: plain cached loads
  const bool xcoh = (grp != 0);

  for (int t = 0; t < SS; ++t) {
    // ---- phase-1 gate (per-wave): kh0 needs own-layer WAR; kh1 needs x[t]
    if (kh == 0)      poll2(selfD, lane, t);
    else if (xcoh)    poll2(prodD, lane, t + 1);

    const u16* A1 = kh ? (Ax + (size_t)t * HH) : Ah;
    float4v az0 = {0,0,0,0}, az1 = {0,0,0,0};
    float4v ar0 = {0,0,0,0}, ar1 = {0,0,0,0};
    float4v ag0 = {0,0,0,0}, ag1 = {0,0,0,0};
    short8 cf[16];

    // chunk 0: ks 0..15
#pragma unroll
    for (int k = 0; k < 16; ++k) {
      const u16* p = A1 + k * 32 + kg * 8;
      cf[k] = (kh == 0 || xcoh) ? coh16(p) : *(const short8*)p;
    }
#pragma unroll
    for (int k = 0; k < 16; ++k) {
      short8 vz = *(const short8*)(wZ + k * 512);
      short8 vr = *(const short8*)(wR + k * 512);
      if (k & 1) { az1 = MFMA16(cf[k], vz, az1); ar1 = MFMA16(cf[k], vr, ar1); }
      else       { az0 = MFMA16(cf[k], vz, az0); ar0 = MFMA16(cf[k], vr, ar0); }
      if (kh == 1) {
        short8 vg = *(const short8*)(wGx + k * 512);
        if (k & 1) ag1 = MFMA16(cf[k], vg, ag1);
        else       ag0 = MFMA16(cf[k], vg, ag0);
      }
    }
    // chunk 1: ks 16..31
#pragma unroll
    for (int k = 0; k < 16; ++k) {
      const u16* p = A1 + (16 + k) * 32 + kg * 8;
      cf[k] = (kh == 0 || xcoh) ? coh16(p) : *(const short8*)p;
    }
#pragma unroll
    for (int k = 0; k < 16; ++k) {
      short8 vz = *(const short8*)(wZ + (16 + k) * 512);
      short8 vr = *(const short8*)(wR + (16 + k) * 512);
      if (k & 1) { az1 = MFMA16(cf[k], vz, az1); ar1 = MFMA16(cf[k], vr, ar1); }
      else       { az0 = MFMA16(cf[k], vz, az0); ar0 = MFMA16(cf[k], vr, ar0); }
      if (kh == 1) {
        short8 vg = *(const short8*)(wGx + (16 + k) * 512);
        if (k & 1) ag1 = MFMA16(cf[k], vg, ag1);
        else       ag0 = MFMA16(cf[k], vg, ag0);
      }
    }
    if (kh == 1) {
#pragma unroll
      for (int q = 0; q < 4; ++q) {
        redz[q][mt][lane] = az0[q] + az1[q];
        redr[q][mt][lane] = ar0[q] + ar1[q];
      }
    }
    __syncthreads();

    if (kh == 0) {
      // finalize z,r; publish r*h; per-wave flag
#pragma unroll
      for (int q = 0; q < 4; ++q) {
        float pz = az0[q] + az1[q] + redz[q][mt][lane] + bzv;
        float pr = ar0[q] + ar1[q] + redr[q][mt][lane] + brv;
        zreg[q] = 1.f / (1.f + expf(-pz));
        float rv = 1.f / (1.f + expf(-pr));
        coh_store_u16(rhl + (crow0 + q) * HH + colZ, f2bf(rv * hreg[q]));
      }
      asm volatile("s_waitcnt vmcnt(0)" ::: "memory");
      if (lane == 0) coh_store_u32(selfP + blk * 2 + mt, t + 1);
    }

    // ---- phase-2 gate: all r*h published
    poll2(selfP, lane, t + 1);

    // rh frags: 16 per wave (K split by kh)
#pragma unroll
    for (int k = 0; k < 16; ++k) cf[k] = coh16(Ar + k * 32 + kg * 8);
#pragma unroll
    for (int k = 0; k < 16; ++k) {
      short8 vg = *(const short8*)(wGh + (kh * 16 + k) * 512);
      if (k & 1) ag1 = MFMA16(cf[k], vg, ag1);
      else       ag0 = MFMA16(cf[k], vg, ag0);
    }
    if (kh == 1) {
#pragma unroll
      for (int q = 0; q < 4; ++q) redg[q][mt][lane] = ag0[q] + ag1[q];
    }
    __syncthreads();

    if (kh == 0) {
#pragma unroll
      for (int q = 0; q < 4; ++q) {
        float pg = ag0[q] + ag1[q] + redg[q][mt][lane] + bgv;
        float gv = tanhf(pg);
        float hn = zreg[q] * hreg[q] + (1.f - zreg[q]) * gv;
        hreg[q] = hn;
        u16 hv = f2bf(hn);
        const int row = crow0 + q;
        coh_store_u16(hbl + row * HH + colZ, hv);
        coh_store_u16(yout + (size_t)row * SH + (size_t)t * HH + colZ, hv);
        if (t == SS - 1) hid[row * (LL * HH) + grp * HH + colZ] = hn;
      }
      asm volatile("s_waitcnt vmcnt(0)" ::: "memory");
      if (lane == 0) coh_store_u32(selfD + blk * 2 + mt, t + 1);
    }
  }
}

// C[16384,1024] = A[16384,1024](bf16) @ W^T(bf16 rows) + bo
__launch_bounds__(64)
__global__ void out_gemm(const u16* __restrict__ A, const u16* __restrict__ W,
                         const float* __restrict__ bo, float* __restrict__ C) {
  const int lane = threadIdx.x;
  const int nt4 = blockIdx.x & 15;
  const int mt4 = blockIdx.x >> 4;
  const int r0 = mt4 * 64, n0 = nt4 * 64;
  const int fcol = lane & 15, kg = lane >> 4;
  float4v acc[4][4];
#pragma unroll
  for (int i = 0; i < 4; ++i)
#pragma unroll
    for (int j = 0; j < 4; ++j) acc[i][j] = (float4v){0, 0, 0, 0};

  for (int ks = 0; ks < 32; ++ks) {
    short8 a[4], b[4];
#pragma unroll
    for (int i = 0; i < 4; ++i)
      a[i] = *(const short8*)(A + (size_t)(r0 + i * 16 + fcol) * HH + ks * 32 + kg * 8);
#pragma unroll
    for (int j = 0; j < 4; ++j)
      b[j] = *(const short8*)(W + (size_t)(n0 + j * 16 + fcol) * HH + ks * 32 + kg * 8);
#pragma unroll
    for (int i = 0; i < 4; ++i)
#pragma unroll
      for (int j = 0; j < 4; ++j)
        acc[i][j] = MFMA16(a[i], b[j], acc[i][j]);
  }
#pragma unroll
  for (int i = 0; i < 4; ++i)
#pragma unroll
    for (int j = 0; j < 4; ++j)
#pragma unroll
      for (int q = 0; q < 4; ++q) {
        int R = r0 + i * 16 + kg * 4 + q;
        int col = n0 + j * 16 + fcol;
        C[(size_t)R * OO + col] = acc[i][j][q] + bo[col];
      }
}

extern "C" void kernel_launch(void* const* d_in, const int* in_sizes, int n_in,
                              void* d_out, int out_size, void* d_ws, size_t ws_size,
                              hipStream_t stream) {
  (void)in_sizes; (void)n_in; (void)out_size; (void)ws_size;

  const float* x   = (const float*)d_in[0];
  const float* h0  = (const float*)d_in[1];
  const float* Wzx = (const float*)d_in[2];
  const float* bz  = (const float*)d_in[3];
  const float* Wzh = (const float*)d_in[4];
  const float* Wrx = (const float*)d_in[5];
  const float* br  = (const float*)d_in[6];
  const float* Wrh = (const float*)d_in[7];
  const float* Wgx = (const float*)d_in[8];
  const float* bg  = (const float*)d_in[9];
  const float* Wgh = (const float*)d_in[10];
  const float* Wo  = (const float*)d_in[11];
  const float* bo  = (const float*)d_in[12];
  float* out = (float*)d_out;

  // ws layout (~103 MB)
  u16* Pzh = (u16*)d_ws;
  u16* Pzx = Pzh + 3145728;
  u16* Prh = Pzx + 3145728;
  u16* Prx = Prh + 3145728;
  u16* Pgh = Prx + 3145728;
  u16* Pgx = Pgh + 3145728;
  u16* Wob = Pgx + 3145728;            // 1M elems
  u16* buf0 = Wob + 1048576;           // 16.7M elems
  u16* buf1 = buf0 + 16777216;
  u16* hbw  = buf1 + 16777216;         // [3][B][H]
  u16* rhw  = hbw + 3 * BB * HH;       // [3][B][H]
  int* flagsD = (int*)(rhw + 3 * BB * HH);  // 4 groups x 128
  int* flagsP = flagsD + 512;               // 3 groups x 128

  hipMemsetAsync(flagsD, 0x7F, 128 * sizeof(int), stream);   // dummy producer
  hipMemsetAsync(flagsD + 128, 0, 384 * sizeof(int), stream);
  hipMemsetAsync(flagsP, 0, 384 * sizeof(int), stream);

  pack_w<<<3072, 256, 0, stream>>>(Wzh, Pzh, 3);
  pack_w<<<3072, 256, 0, stream>>>(Wzx, Pzx, 3);
  pack_w<<<3072, 256, 0, stream>>>(Wrh, Prh, 3);
  pack_w<<<3072, 256, 0, stream>>>(Wrx, Prx, 3);
  pack_w<<<3072, 256, 0, stream>>>(Wgh, Pgh, 3);
  pack_w<<<3072, 256, 0, stream>>>(Wgx, Pgx, 3);
  convert_bf16<<<256, 256, 0, stream>>>(Wo, Wob, 1048576);
  convert_bf16<<<2048, 256, 0, stream>>>(x, buf0, 16777216);
  init_h<<<384, 256, 0, stream>>>(h0, hbw);

  gru_pipe<<<192, 256, 0, stream>>>(
      buf0, buf1, Pzh, Pzx, Prh, Prx, Pgh, Pgx,
      bz, br, bg, h0, hbw, rhw, out + 16777216, flagsD, flagsP);

  out_gemm<<<4096, 64, 0, stream>>>(buf1, Wob, bo, out);
}